// Round 9
// baseline (146.574 us; speedup 1.0000x reference)
//
#include <hip/hip_runtime.h>
#include <math.h>

#define CCH 512      // channels
#define FH 76        // feature H
#define FW 128       // feature W
#define NP 256       // proposals
#define HID 200      // hidden width
#define NKC 16       // K-chunks for layer1 split-K (128 k each)
#define NTILE 32     // proposal tiles of 8
#define FM4 (FH * FW * (CCH / 4))      // 1,245,184 float4 in feature map
#define PG_THREADS (512 * 512)         // threads in fused grid

// ---- ws layout ----
// part : [16][256][200] fp32 (3.3 MB)
// cnt  : 32 uints, 128B-strided (zeroed by hipMemsetAsync each launch)
// scratch : DCE guard target

// ------------- fused: warm + ROI-pool + layer1 + (finisher) head -------------
// R8 structure (measured best: 120.6us) plus a spin-free last-finisher join:
// the (tile, kc) grid exactly tiles f[256][2048]; each block pools its
// [8 proposals x 128 ch] subtile into LDS and GEMMs it against its W1 chunk.
// After writing its part chunk, each block does threadfence + agent-scope
// atomicAdd(cnt[tile]); the 16th arrival (old==15) inherits the MLP-head for
// the tile's 8 proposals. No spinning (R6: grid barriers cost ~50us); the
// head work overlaps other tiles' pool/GEMM phases; one dispatch disappears.
// Phase A warm: harness restores inputs then poisons 268MB ws (cycles all of
// L2+L3), so every input is HBM-cold; stream fm+W1+W2 coalesced at HBM BW so
// scattered/strided reads hit cache (~200cyc) instead of cold HBM (~900cyc).
__global__ __launch_bounds__(512) void fused_kernel(
    const float4* __restrict__ fm4, const int* __restrict__ coords,
    const float* __restrict__ W1, const float* __restrict__ b1,
    const float* __restrict__ W2, const float* __restrict__ b2,
    const float* __restrict__ W3, const float* __restrict__ b3,
    const float* __restrict__ W4, const float* __restrict__ b4,
    float* __restrict__ part, unsigned int* __restrict__ cnt,
    float* __restrict__ scratch, float* __restrict__ out)
{
    __shared__ float4 sm[2][8][32];    // pool: rslot x proposal x f4-group
    __shared__ float  fsub[8][128];    // pooled subtile
    __shared__ float  pc[2][8][HID];   // GEMM K-half partials
    __shared__ float  pbuf[2][8][HID]; // head: partials (reused l1-red / l2)
    __shared__ float  hbuf[8][HID];    // head: h1 then h2
    __shared__ float  hdp[2][8][21];
    __shared__ float  hd[8][21];
    __shared__ int    winner;

    const int t   = threadIdx.x;
    const int r0  = blockIdx.x * 8;          // 32 tiles of 8 proposals
    const int kc  = blockIdx.y;              // 0..15
    const int bin = kc >> 2;
    const int cb  = (kc & 3) * 32;           // f4-group offset inside bin
    const int k0  = kc * 128;                // global k offset

    // ===== Phase A: cooperative cache warm (fm + W1 + W2) =====
    {
        const int gtid = (blockIdx.y * NTILE + blockIdx.x) * 512 + t;
        float wacc = -1e30f;
        #pragma unroll
        for (int i = 0; i < 5; ++i) {        // 5 x 262144 >= FM4
            const int idx = gtid + i * PG_THREADS;
            if (idx < FM4) {
                const float4 v = fm4[idx];
                wacc = fmaxf(wacc, fmaxf(fmaxf(v.x, v.y), fmaxf(v.z, v.w)));
            }
        }
        if (gtid < 102400) {                 // W1: 2048*200/4 float4
            const float4 v = ((const float4*)W1)[gtid];
            wacc = fmaxf(wacc, fmaxf(fmaxf(v.x, v.y), fmaxf(v.z, v.w)));
        }
        if (gtid < 10000) {                  // W2: 200*200/4 float4
            const float4 v = ((const float4*)W2)[gtid];
            wacc = fmaxf(wacc, fmaxf(fmaxf(v.x, v.y), fmaxf(v.z, v.w)));
        }
        // DCE guard: data-dependent, never true for N(0,1)-scale inputs.
        if (wacc > 1e29f) scratch[0] = wacc;
    }

    // ===== Phase B: pool this block's [8 proposals x 128 ch] subtile =====
    {
        const int rslot = t >> 8;            // 0..1 (wave-uniform)
        const int nl    = (t >> 5) & 7;      // proposal within tile
        const int cg    = t & 31;            // f4-group within chunk
        const int n  = r0 + nl;
        const int c0 = coords[n*4+0], c1 = coords[n*4+1];
        const int c2 = coords[n*4+2], c3 = coords[n*4+3];
        const int sy = min(c0 >> 3, FH - 2);
        const int sx = min(c1 >> 3, FW - 2);
        const int h = max(((c2 + 7) >> 3) - sy, 2);
        const int w = max(((c3 + 7) >> 3) - sx, 2);
        const int by = bin >> 1, bx = bin & 1;
        // adaptive bin i covers [i*size/2, ((i+1)*size+1)/2)
        const int rs = by ? (h >> 1) : 0;
        const int re = by ? h : ((h + 1) >> 1);
        const int cs = bx ? (w >> 1) : 0;
        const int ce = bx ? w : ((w + 1) >> 1);
        const int nc = ce - cs;              // 1..12 cols
        float4 m = make_float4(-1e30f, -1e30f, -1e30f, -1e30f);
        for (int r = rs + rslot; r < re; r += 2) {
            const float4* row = fm4 +
                ((size_t)(sy + r) * FW + sx + cs) * (CCH/4) + cb + cg;
            #pragma unroll 4
            for (int cc = 0; cc < nc; ++cc) {
                const float4 v = row[(size_t)cc * (CCH/4)];
                m.x = fmaxf(m.x, v.x); m.y = fmaxf(m.y, v.y);
                m.z = fmaxf(m.z, v.z); m.w = fmaxf(m.w, v.w);
            }
        }
        sm[rslot][nl][cg] = m;
    }
    __syncthreads();
    if (t < 256) {
        const int nl = t >> 5, cg = t & 31;
        const float4 a = sm[0][nl][cg], b = sm[1][nl][cg];
        float4 o;
        o.x = fmaxf(a.x, b.x); o.y = fmaxf(a.y, b.y);
        o.z = fmaxf(a.z, b.z); o.w = fmaxf(a.w, b.w);
        *((float4*)&fsub[nl][cg * 4]) = o;
    }
    __syncthreads();

    // ===== Phase C: GEMM chunk — part[kc][r0+r][j] over 128 k =====
    const int half = t >> 8;                 // 0..1 (wave-uniform)
    const int j    = t & 255;
    if (j < HID) {
        float acc[8];
        #pragma unroll
        for (int r = 0; r < 8; ++r) acc[r] = 0.0f;
        const int kk0 = half * 64;
        const float* wp = W1 + (size_t)(k0 + kk0) * HID + j;   // coalesced in j
        #pragma unroll 8
        for (int kk = 0; kk < 64; ++kk) {
            const float wv = wp[(size_t)kk * HID];
            #pragma unroll
            for (int r = 0; r < 8; ++r)
                acc[r] += fsub[r][kk0 + kk] * wv;              // LDS broadcast
        }
        #pragma unroll
        for (int r = 0; r < 8; ++r) pc[half][r][j] = acc[r];
    }
    __syncthreads();
    if (t < HID) {
        float* pp = part + ((size_t)kc * NP + r0) * HID + t;
        #pragma unroll
        for (int r = 0; r < 8; ++r)
            pp[(size_t)r * HID] = pc[0][r][t] + pc[1][r][t];
    }
    __syncthreads();   // drains the part stores (waitcnt vmcnt(0) + barrier)

    // ===== Finisher join: 16th block for this tile inherits the head =====
    if (t == 0) {
        __threadfence();   // release: this block's part chunk -> visible
        const unsigned int old = __hip_atomic_fetch_add(
            &cnt[blockIdx.x * 32], 1u, __ATOMIC_ACQ_REL,
            __HIP_MEMORY_SCOPE_AGENT);
        winner = (old == NKC - 1);
        if (winner) __threadfence();   // acquire: see the other 15 chunks
    }
    __syncthreads();
    if (!winner) return;

    // ===== Head (winner block only): 8 proposals of this tile =====
    // h1 partials: thread (j, half) sums 8 kc's for 8 proposals
    if (j < HID) {
        float acc[8];
        #pragma unroll
        for (int r = 0; r < 8; ++r) acc[r] = 0.0f;
        #pragma unroll
        for (int c = 0; c < 8; ++c) {
            const int kk = half * 8 + c;
            #pragma unroll
            for (int r = 0; r < 8; ++r)
                acc[r] += part[((size_t)kk * NP + r0 + r) * HID + j];
        }
        #pragma unroll
        for (int r = 0; r < 8; ++r) pbuf[half][r][j] = acc[r];
    }
    __syncthreads();
    if (t < HID) {
        #pragma unroll
        for (int r = 0; r < 8; ++r)
            hbuf[r][t] = fmaxf(pbuf[0][r][t] + pbuf[1][r][t] + b1[t], 0.0f);
    }
    __syncthreads();
    // layer2 partials: W2 load reused across the 8 proposals
    if (j < HID) {
        float acc[8];
        #pragma unroll
        for (int r = 0; r < 8; ++r) acc[r] = 0.0f;
        const int kk0 = half * 100;
        #pragma unroll 4
        for (int k = 0; k < 100; ++k) {
            const float wv = W2[(kk0 + k) * HID + j];
            #pragma unroll
            for (int r = 0; r < 8; ++r)
                acc[r] += hbuf[r][kk0 + k] * wv;
        }
        #pragma unroll
        for (int r = 0; r < 8; ++r) pbuf[half][r][j] = acc[r];
    }
    __syncthreads();
    if (t < HID) {
        #pragma unroll
        for (int r = 0; r < 8; ++r)
            hbuf[r][t] = fmaxf(pbuf[0][r][t] + pbuf[1][r][t] + b2[t], 0.0f);
    }
    __syncthreads();
    // heads: 21 outputs (16 reg + 5 cls) x 8 proposals
    if (j < 21) {
        float acc[8];
        #pragma unroll
        for (int r = 0; r < 8; ++r) acc[r] = 0.0f;
        const int kk0 = half * 100;
        #pragma unroll 4
        for (int k = 0; k < 100; ++k) {
            const float wv = (j < 16) ? W3[(kk0 + k) * 16 + j]
                                      : W4[(kk0 + k) * 5 + (j - 16)];
            #pragma unroll
            for (int r = 0; r < 8; ++r)
                acc[r] += hbuf[r][kk0 + k] * wv;
        }
        #pragma unroll
        for (int r = 0; r < 8; ++r) hdp[half][r][j] = acc[r];
    }
    __syncthreads();
    if (t < 168) {
        const int r = t / 21, jj = t % 21;
        hd[r][jj] = hdp[0][r][jj] + hdp[1][r][jj]
                  + (jj < 16 ? b3[jj] : b4[jj - 16]);
    }
    __syncthreads();
    if (t < 8) {
        const int n = r0 + t;
        const float cv0 = hd[t][16], cv1 = hd[t][17], cv2 = hd[t][18],
                    cv3 = hd[t][19], cv4 = hd[t][20];
        // jnp.argmax: first occurrence of max -> strict '>'
        int cls = 0; float best = cv0;
        if (cv1 > best) { best = cv1; cls = 1; }
        if (cv2 > best) { best = cv2; cls = 2; }
        if (cv3 > best) { best = cv3; cls = 3; }
        if (cv4 > best) { best = cv4; cls = 4; }
        const float e0 = expf(cv0 - best), e1 = expf(cv1 - best),
                    e2 = expf(cv2 - best), e3 = expf(cv3 - best),
                    e4 = expf(cv4 - best);
        const float s = e0 + e1 + e2 + e3 + e4;
        const float score = fmaxf(fmaxf(e1, e2), fmaxf(e3, e4)) / s;
        const int ri = max(cls - 1, 0);
        const float rg0 = hd[t][ri*4+0], rg1 = hd[t][ri*4+1],
                    rg2 = hd[t][ri*4+2], rg3 = hd[t][ri*4+3];
        const float y0 = (float)coords[n*4+0], x0 = (float)coords[n*4+1];
        const float y1 = (float)coords[n*4+2], x1 = (float)coords[n*4+3];
        const float ph = y1 - y0, pw = x1 - x0;
        const float py = y0 + 0.5f * ph, px = x0 + 0.5f * pw;
        const float oy = ph * rg0 + py;
        const float ox = pw * rg1 + px;
        const float oh = ph * fminf(fmaxf(expf(rg2), 0.001f), 20.0f);
        const float ow = pw * fminf(fmaxf(expf(rg3), 0.001f), 20.0f);
        out[n*4+0] = oy; out[n*4+1] = ox; out[n*4+2] = oh; out[n*4+3] = ow;
        out[NP*4 + n] = score;                       // scores block
        out[NP*5 + n] = (cls != 0) ? 1.0f : 0.0f;    // mask block (bool as fp32)
    }
}

extern "C" void kernel_launch(void* const* d_in, const int* in_sizes, int n_in,
                              void* d_out, int out_size, void* d_ws, size_t ws_size,
                              hipStream_t stream) {
    const float* fm     = (const float*)d_in[0];   // [1,76,128,512]
    const int*   coords = (const int*)  d_in[1];   // [256,4]
    const float* W1 = (const float*)d_in[2];       // [2048,200]
    const float* b1 = (const float*)d_in[3];
    const float* W2 = (const float*)d_in[4];       // [200,200]
    const float* b2 = (const float*)d_in[5];
    const float* W3 = (const float*)d_in[6];       // [200,16]
    const float* b3 = (const float*)d_in[7];
    const float* W4 = (const float*)d_in[8];       // [200,5]
    const float* b4 = (const float*)d_in[9];
    float* out = (float*)d_out;                    // 1024 boxes + 256 scores + 256 mask

    float*        part    = (float*)d_ws;          // [16, 256, 200]
    unsigned int* cnt     = (unsigned int*)(part + (size_t)NKC * NP * HID);
    float*        scratch = (float*)(cnt + NTILE * 32);

    // zero the 32 finisher counters (ws arrives 0xAA-poisoned)
    hipMemsetAsync(cnt, 0, NTILE * 32 * sizeof(unsigned int), stream);
    fused_kernel<<<dim3(NTILE, NKC), 512, 0, stream>>>(
        (const float4*)fm, coords, W1, b1, W2, b2, W3, b3, W4, b4,
        part, cnt, scratch, out);
}

// Round 10
// 120.294 us; speedup vs baseline: 1.2185x; 1.2185x over previous
//
#include <hip/hip_runtime.h>
#include <math.h>

#define CCH 512      // channels
#define FH 76        // feature H
#define FW 128       // feature W
#define NP 256       // proposals
#define HID 200      // hidden width
#define NKC 16       // K-chunks for layer1 split-K (128 k each)
#define FM4 (FH * FW * (CCH / 4))      // 1,245,184 float4 in feature map
#define PG_THREADS (512 * 512)         // threads in poolgemm grid

// ---------------- Kernel 1: fused warm + ROI-pool + layer1 split-K ------
// R8 measured best (120.6us). The (row-tile, kc) split-K grid EXACTLY tiles
// the pooled feature matrix f[256][2048]: k-chunk kc covers bin kc>>2,
// channel block (kc&3)*128. Each block pools its own [8 proposals x 128 ch]
// f-subtile into LDS and immediately GEMMs it against its W1 chunk —
// no inter-block dependency, no f global round-trip.
// Phase A warm: the harness restores inputs then poisons 268MB of ws
// (cycles all of L2+L3), so every input is HBM-cold at kernel start;
// streaming fm+W1 coalesced pulls them into cache so the scattered pool
// reads and strided W1 reads hit ~200cyc instead of cold-HBM ~900cyc.
// MEASURED LESSONS (do not revisit):
//  - R5: separate warm dispatch costs more than its ordering gain (+1.8us).
//  - R6: software grid barriers cost ~50us each at 256 blocks.
//  - R9: per-block __threadfence joins (last-finisher) force L2 writebacks
//    that re-cold the warm cache -> fused kernel 72us. Cross-block joins
//    must live at dispatch boundaries (~2us each).
__global__ __launch_bounds__(512) void poolgemm_kernel(
    const float4* __restrict__ fm4, const int* __restrict__ coords,
    const float* __restrict__ W1, float* __restrict__ part,
    float* __restrict__ scratch)
{
    __shared__ float4 sm[2][8][32];    // rslot x proposal x f4-group (8 KB)
    __shared__ float  fsub[8][128];    // pooled subtile (4 KB)
    __shared__ float  pc[2][8][HID];   // K-half partials (12.8 KB)

    const int t   = threadIdx.x;
    const int r0  = blockIdx.x * 8;          // 32 row-tiles
    const int kc  = blockIdx.y;              // 0..15
    const int bin = kc >> 2;
    const int cb  = (kc & 3) * 32;           // f4-group offset inside bin
    const int k0  = kc * 128;                // global k offset

    // ===== Phase A: cooperative cache warm (fm + W1) =====
    {
        const int gtid = (blockIdx.y * 32 + blockIdx.x) * 512 + t;
        float wacc = -1e30f;
        #pragma unroll
        for (int i = 0; i < 5; ++i) {        // 5 x 262144 >= FM4
            const int idx = gtid + i * PG_THREADS;
            if (idx < FM4) {
                const float4 v = fm4[idx];
                wacc = fmaxf(wacc, fmaxf(fmaxf(v.x, v.y), fmaxf(v.z, v.w)));
            }
        }
        if (gtid < 102400) {                 // W1: 2048*200/4 float4
            const float4 v = ((const float4*)W1)[gtid];
            wacc = fmaxf(wacc, fmaxf(fmaxf(v.x, v.y), fmaxf(v.z, v.w)));
        }
        // DCE guard: data-dependent, never true for N(0,1)-scale inputs.
        if (wacc > 1e29f) scratch[0] = wacc;
    }

    // ===== Phase B: pool this block's [8 proposals x 128 ch] subtile =====
    {
        const int rslot = t >> 8;            // 0..1 (wave-uniform)
        const int nl    = (t >> 5) & 7;      // proposal within tile
        const int cg    = t & 31;            // f4-group within chunk
        const int n  = r0 + nl;
        const int c0 = coords[n*4+0], c1 = coords[n*4+1];
        const int c2 = coords[n*4+2], c3 = coords[n*4+3];
        const int sy = min(c0 >> 3, FH - 2);
        const int sx = min(c1 >> 3, FW - 2);
        const int h = max(((c2 + 7) >> 3) - sy, 2);
        const int w = max(((c3 + 7) >> 3) - sx, 2);
        const int by = bin >> 1, bx = bin & 1;
        // adaptive bin i covers [i*size/2, ((i+1)*size+1)/2)
        const int rs = by ? (h >> 1) : 0;
        const int re = by ? h : ((h + 1) >> 1);
        const int cs = bx ? (w >> 1) : 0;
        const int ce = bx ? w : ((w + 1) >> 1);
        const int nc = ce - cs;              // 1..12 cols
        float4 m = make_float4(-1e30f, -1e30f, -1e30f, -1e30f);
        for (int r = rs + rslot; r < re; r += 2) {
            const float4* row = fm4 +
                ((size_t)(sy + r) * FW + sx + cs) * (CCH/4) + cb + cg;
            #pragma unroll 4
            for (int cc = 0; cc < nc; ++cc) {
                const float4 v = row[(size_t)cc * (CCH/4)];
                m.x = fmaxf(m.x, v.x); m.y = fmaxf(m.y, v.y);
                m.z = fmaxf(m.z, v.z); m.w = fmaxf(m.w, v.w);
            }
        }
        sm[rslot][nl][cg] = m;
    }
    __syncthreads();
    if (t < 256) {
        const int nl = t >> 5, cg = t & 31;
        const float4 a = sm[0][nl][cg], b = sm[1][nl][cg];
        float4 o;
        o.x = fmaxf(a.x, b.x); o.y = fmaxf(a.y, b.y);
        o.z = fmaxf(a.z, b.z); o.w = fmaxf(a.w, b.w);
        *((float4*)&fsub[nl][cg * 4]) = o;   // 16B-aligned LDS store
    }
    __syncthreads();

    // ===== Phase C: GEMM chunk — part[kc][r0+r][j] over 128 k =====
    {
        const int half = t >> 8;             // K-half 0..1 (wave-uniform)
        const int j    = t & 255;
        if (j < HID) {
            float acc[8];
            #pragma unroll
            for (int r = 0; r < 8; ++r) acc[r] = 0.0f;
            const int kk0 = half * 64;
            const float* wp = W1 + (size_t)(k0 + kk0) * HID + j;  // coalesced in j
            #pragma unroll 8
            for (int kk = 0; kk < 64; ++kk) {
                const float wv = wp[(size_t)kk * HID];
                #pragma unroll
                for (int r = 0; r < 8; ++r)
                    acc[r] += fsub[r][kk0 + kk] * wv;   // LDS broadcast
            }
            #pragma unroll
            for (int r = 0; r < 8; ++r) pc[half][r][j] = acc[r];
        }
    }
    __syncthreads();
    if (t < HID) {
        float* pp = part + ((size_t)kc * NP + r0) * HID + t;
        #pragma unroll
        for (int r = 0; r < 8; ++r)
            pp[(size_t)r * HID] = pc[0][r][t] + pc[1][r][t];
    }
}

// ---------------- Kernel 2: reduce + layer2 + heads + postprocess --------
// One block (512 threads) per proposal; layer2 and heads are split over
// 2 K-halves (kc = t>>8, wave-uniform) to halve the serial load chains.
__global__ __launch_bounds__(512) void head_kernel(
    const float* __restrict__ part,
    const float* __restrict__ b1, const float* __restrict__ W2,
    const float* __restrict__ b2, const float* __restrict__ W3,
    const float* __restrict__ b3, const float* __restrict__ W4,
    const float* __restrict__ b4, const int* __restrict__ coords,
    float* __restrict__ out)
{
    __shared__ float h1s[HID];
    __shared__ float h2s[HID];
    __shared__ float p2[2][HID];
    __shared__ float hdp[2][21];
    __shared__ float hd[21];     // 16 reg + 5 cls
    const int n = blockIdx.x;
    const int t = threadIdx.x;
    const int kc = t >> 8;       // 0..1, wave-uniform
    const int j  = t & 255;
    if (t < HID) {
        float a = b1[t];
        #pragma unroll
        for (int c = 0; c < NKC; ++c)
            a += part[((size_t)c * NP + n) * HID + t];
        h1s[t] = fmaxf(a, 0.0f);
    }
    __syncthreads();
    if (j < HID) {
        const int k0 = kc * 100;
        float acc = 0.0f;
        #pragma unroll 10
        for (int k = 0; k < 100; ++k)
            acc += h1s[k0 + k] * W2[(k0 + k) * HID + j];
        p2[kc][j] = acc;
    }
    __syncthreads();
    if (t < HID) h2s[t] = fmaxf(p2[0][t] + p2[1][t] + b2[t], 0.0f);
    __syncthreads();
    if (j < 21) {
        const int k0 = kc * 100;
        float acc = 0.0f;
        if (j < 16) {
            #pragma unroll 5
            for (int k = 0; k < 100; ++k)
                acc += h2s[k0 + k] * W3[(k0 + k) * 16 + j];
        } else {
            const int ci = j - 16;
            #pragma unroll 5
            for (int k = 0; k < 100; ++k)
                acc += h2s[k0 + k] * W4[(k0 + k) * 5 + ci];
        }
        hdp[kc][j] = acc;
    }
    __syncthreads();
    if (t < 21)
        hd[t] = hdp[0][t] + hdp[1][t] + (t < 16 ? b3[t] : b4[t - 16]);
    __syncthreads();
    if (t == 0) {
        const float cv0 = hd[16], cv1 = hd[17], cv2 = hd[18],
                    cv3 = hd[19], cv4 = hd[20];
        // jnp.argmax: first occurrence of max -> strict '>'
        int cls = 0; float best = cv0;
        if (cv1 > best) { best = cv1; cls = 1; }
        if (cv2 > best) { best = cv2; cls = 2; }
        if (cv3 > best) { best = cv3; cls = 3; }
        if (cv4 > best) { best = cv4; cls = 4; }
        const float e0 = expf(cv0 - best), e1 = expf(cv1 - best),
                    e2 = expf(cv2 - best), e3 = expf(cv3 - best),
                    e4 = expf(cv4 - best);
        const float s = e0 + e1 + e2 + e3 + e4;
        const float score = fmaxf(fmaxf(e1, e2), fmaxf(e3, e4)) / s;
        const int ri = max(cls - 1, 0);
        const float rg0 = hd[ri*4+0], rg1 = hd[ri*4+1],
                    rg2 = hd[ri*4+2], rg3 = hd[ri*4+3];
        const float y0 = (float)coords[n*4+0], x0 = (float)coords[n*4+1];
        const float y1 = (float)coords[n*4+2], x1 = (float)coords[n*4+3];
        const float ph = y1 - y0, pw = x1 - x0;
        const float py = y0 + 0.5f * ph, px = x0 + 0.5f * pw;
        const float oy = ph * rg0 + py;
        const float ox = pw * rg1 + px;
        const float oh = ph * fminf(fmaxf(expf(rg2), 0.001f), 20.0f);
        const float ow = pw * fminf(fmaxf(expf(rg3), 0.001f), 20.0f);
        out[n*4+0] = oy; out[n*4+1] = ox; out[n*4+2] = oh; out[n*4+3] = ow;
        out[NP*4 + n] = score;                       // scores block
        out[NP*5 + n] = (cls != 0) ? 1.0f : 0.0f;    // mask block (bool as fp32)
    }
}

extern "C" void kernel_launch(void* const* d_in, const int* in_sizes, int n_in,
                              void* d_out, int out_size, void* d_ws, size_t ws_size,
                              hipStream_t stream) {
    const float* fm     = (const float*)d_in[0];   // [1,76,128,512]
    const int*   coords = (const int*)  d_in[1];   // [256,4]
    const float* W1 = (const float*)d_in[2];       // [2048,200]
    const float* b1 = (const float*)d_in[3];
    const float* W2 = (const float*)d_in[4];       // [200,200]
    const float* b2 = (const float*)d_in[5];
    const float* W3 = (const float*)d_in[6];       // [200,16]
    const float* b3 = (const float*)d_in[7];
    const float* W4 = (const float*)d_in[8];       // [200,5]
    const float* b4 = (const float*)d_in[9];
    float* out = (float*)d_out;                    // 1024 boxes + 256 scores + 256 mask

    float* part    = (float*)d_ws;                 // [16, 256, 200]
    float* scratch = part + (size_t)NKC * NP * HID;

    poolgemm_kernel<<<dim3(32, NKC), 512, 0, stream>>>(
        (const float4*)fm, coords, W1, part, scratch);
    head_kernel<<<NP, 512, 0, stream>>>(part, b1, W2, b2, W3, b3, W4, b4,
                                        coords, out);
}